// Round 1
// baseline (1608.471 us; speedup 1.0000x reference)
//
#include <hip/hip_runtime.h>
#include <hip/hip_bf16.h>

// EnKF-LSTM (LS=1, BS=32, NH=256, NE=64, SEQ=64, DIN=256, MOBS=64)
// Pipeline: xW precompute -> f16 MFMA LSTM (64 blocks, 16 seqs each, no
// cross-block sync) -> obs/cov -> LDL^T solve + T=HA^T sol -> state update
// -> obs/cov (mu,sig) -> loglik (LDL, quad, logdet) -> reduce (l, nis).

typedef _Float16 f16;
typedef _Float16 f16x8 __attribute__((ext_vector_type(8)));
typedef float f32x4 __attribute__((ext_vector_type(4)));

#define BS   32
#define NH   256
#define NE   64
#define SEQQ 64
#define DIN  256
#define MOBS 64
#define G4   1024

__device__ __forceinline__ float fast_sigmoid(float x) {
  return __builtin_amdgcn_rcpf(1.f + __expf(-x));
}
__device__ __forceinline__ float fast_tanh(float x) {
  return 2.f * __builtin_amdgcn_rcpf(1.f + __expf(-2.f * x)) - 1.f;
}

// ---------------- K1: xWb = x @ W_ih + b  (2048x1024, K=256, fp32) ---------
__global__ __launch_bounds__(256)
void k_xw(const float* __restrict__ x, const float* __restrict__ W_ih,
          const float* __restrict__ bv, float* __restrict__ xWb) {
  __shared__ float xs[8][DIN];
  const int tid = threadIdx.x;
  const int m0 = blockIdx.x * 8;  // 256 blocks x 8 rows
  for (int idx = tid; idx < 8 * DIN; idx += 256)
    xs[idx >> 8][idx & 255] = x[m0 * DIN + idx];
  __syncthreads();
  float acc[8][4];
#pragma unroll
  for (int r = 0; r < 8; ++r)
#pragma unroll
    for (int j = 0; j < 4; ++j) acc[r][j] = 0.f;
  for (int k = 0; k < DIN; ++k) {
    float w0 = W_ih[k * G4 + tid];
    float w1 = W_ih[k * G4 + 256 + tid];
    float w2 = W_ih[k * G4 + 512 + tid];
    float w3 = W_ih[k * G4 + 768 + tid];
#pragma unroll
    for (int r = 0; r < 8; ++r) {
      float xv = xs[r][k];
      acc[r][0] += xv * w0; acc[r][1] += xv * w1;
      acc[r][2] += xv * w2; acc[r][3] += xv * w3;
    }
  }
#pragma unroll
  for (int r = 0; r < 8; ++r)
#pragma unroll
    for (int j = 0; j < 4; ++j)
      xWb[(m0 + r) * G4 + j * 256 + tid] = acc[r][j] + bv[j * 256 + tid];
}

// ---------------- K2: pack W_hh^T (f16, [1024][256]) + Wh (f16) ------------
__global__ __launch_bounds__(256)
void k_pack(const float* __restrict__ W_hh, const float* __restrict__ Wh,
            f16* __restrict__ WhhT, f16* __restrict__ Whf) {
  int idx = blockIdx.x * 256 + threadIdx.x;
  if (idx < G4 * DIN) {
    int n = idx >> 8, k = idx & 255;
    WhhT[idx] = (f16)W_hh[k * G4 + n];
  } else {
    int i2 = idx - G4 * DIN;
    if (i2 < MOBS * NH) Whf[i2] = (f16)Wh[i2];
  }
}

// ---------------- K3: LSTM recurrence (f16 MFMA) ---------------------------
// 64 blocks: block = (member e, 16 batch rows). gates = h @ W_hh via
// mfma_f32_16x16x32_f16; xW part + elementwise in fp32; c in registers.
__global__ __launch_bounds__(256, 1)
void k_lstm(const float* __restrict__ xWb, const f16* __restrict__ WhhT,
            const float* __restrict__ enkf, const float* __restrict__ eps_h,
            const float* __restrict__ eps_c, const float* __restrict__ qp,
            const float* __restrict__ ep, float* __restrict__ stateF) {
  __shared__ __align__(16) f16 hs[16 * 264];     // [row][k], pad 8
  __shared__ float gates[16 * 1028];             // [row][gatecol], pad 4
  const int tid = threadIdx.x;
  const int e = blockIdx.x >> 1;
  const int b0 = (blockIdx.x & 1) * 16;
  const int lane = tid & 63;
  const int wave = tid >> 6;
  const int c0 = lane & 15;
  const int qd = lane >> 4;

  float creg[16];
  {
    const int j = tid;  // hidden index owned by this thread
#pragma unroll 4
    for (int r = 0; r < 16; ++r) {
      float hv = enkf[((b0 + r) * NH + j) * NE + e];
      creg[r]  = enkf[((b0 + r) * NH + j) * NE + 32 + e];
      hs[r * 264 + j] = (f16)hv;
    }
  }
  __syncthreads();

  const float nq = fabsf(qp[0]);
  const float nee = fabsf(ep[0]);

  for (int t = 0; t < SEQQ; ++t) {
    // A-fragments: h rows (m = c0), k contiguous
    f16x8 afr[8];
#pragma unroll
    for (int ks = 0; ks < 8; ++ks)
      afr[ks] = *(const f16x8*)&hs[c0 * 264 + ks * 32 + qd * 8];
    // each wave: 16 n-tiles (cols wave*256 .. wave*256+255)
#pragma unroll 2
    for (int ntl = 0; ntl < 16; ++ntl) {
      const int ncol = (wave * 16 + ntl) * 16;
      const f16* wp = &WhhT[(ncol + c0) * DIN + qd * 8];
      f32x4 acc = {0.f, 0.f, 0.f, 0.f};
#pragma unroll
      for (int ks = 0; ks < 8; ++ks) {
        f16x8 bfr = *(const f16x8*)(wp + ks * 32);
        acc = __builtin_amdgcn_mfma_f32_16x16x32_f16(afr[ks], bfr, acc, 0, 0, 0);
      }
#pragma unroll
      for (int q = 0; q < 4; ++q)
        gates[(qd * 4 + q) * 1028 + ncol + c0] = acc[q];
    }
    __syncthreads();
    // elementwise: thread owns hidden j = tid for all 16 rows
    {
      const int j = tid;
      const float* xr0 = xWb + (size_t)(b0 * 64 + t) * G4 + j;
      const bool last = (t == SEQQ - 1);
#pragma unroll 4
      for (int r = 0; r < 16; ++r) {
        const float* xr = xr0 + (size_t)r * 64 * G4;
        float iv = gates[r * 1028 + j]        + xr[0];
        float fv = gates[r * 1028 + 256 + j]  + xr[256];
        float gv = gates[r * 1028 + 512 + j]  + xr[512];
        float ov = gates[r * 1028 + 768 + j]  + xr[768];
        float c2 = fast_sigmoid(fv) * creg[r] + fast_sigmoid(iv) * fast_tanh(gv);
        float h2 = fast_sigmoid(ov) * fast_tanh(c2);
        creg[r] = c2;
        hs[r * 264 + j] = (f16)h2;
        if (last) {
          stateF[((b0 + r) * NH + j) * NE + e] =
              h2 + nq * eps_h[(e * BS + b0 + r) * NH + j];
          stateF[((b0 + r) * NH + j) * NE + 32 + e] =
              c2 + nee * eps_c[(e * BS + b0 + r) * NH + j];
        }
      }
    }
    __syncthreads();
  }
}

// ---------------- K4: obs + mean + cov (per batch) -------------------------
// hxi = Wh@state + bh ; mean over ensemble ; cov = HA HA^T/63 + r^2 I
__global__ __launch_bounds__(256)
void k_obscov(const float* __restrict__ state, const f16* __restrict__ Whf,
              const float* __restrict__ bh, const float* __restrict__ rp,
              float* __restrict__ hxi_g, float* __restrict__ mean_g,
              float* __restrict__ cov_g, int write_hxi) {
  __shared__ __align__(16) f16 stT[64 * 264];   // [j][k=nh]
  __shared__ float hxl[64 * 66];
  __shared__ float hxm[64];
  __shared__ __align__(16) f16 HAf[64 * 72];    // [m][j]
  const int tid = threadIdx.x;
  const int b = blockIdx.x;
  const int lane = tid & 63, wave = tid >> 6;
  const int c0 = lane & 15, qd = lane >> 4;

  for (int idx = tid; idx < NH * NE; idx += 256) {
    int k = idx >> 6, j = idx & 63;
    stT[j * 264 + k] = (f16)state[b * (NH * NE) + idx];
  }
  __syncthreads();
  {
    f16x8 afr[8];
#pragma unroll
    for (int ks = 0; ks < 8; ++ks)
      afr[ks] = *(const f16x8*)&Whf[(wave * 16 + c0) * DIN + ks * 32 + qd * 8];
    for (int nt = 0; nt < 4; ++nt) {
      f32x4 acc = {0.f, 0.f, 0.f, 0.f};
#pragma unroll
      for (int ks = 0; ks < 8; ++ks) {
        f16x8 bfr = *(const f16x8*)&stT[(nt * 16 + c0) * 264 + ks * 32 + qd * 8];
        acc = __builtin_amdgcn_mfma_f32_16x16x32_f16(afr[ks], bfr, acc, 0, 0, 0);
      }
#pragma unroll
      for (int q = 0; q < 4; ++q) {
        int m = wave * 16 + qd * 4 + q;
        int j = nt * 16 + c0;
        float v = acc[q] + bh[m];
        hxl[m * 66 + j] = v;
        if (write_hxi) hxi_g[b * (MOBS * NE) + m * NE + j] = v;
      }
    }
  }
  __syncthreads();
  if (tid < 64) {
    float s = 0.f;
    for (int j = 0; j < 64; ++j) s += hxl[tid * 66 + j];
    s *= (1.f / 64.f);
    hxm[tid] = s;
    mean_g[b * MOBS + tid] = s;
  }
  __syncthreads();
  for (int idx = tid; idx < 64 * 64; idx += 256) {
    int m = idx >> 6, j = idx & 63;
    HAf[m * 72 + j] = (f16)(hxl[m * 66 + j] - hxm[m]);
  }
  __syncthreads();
  {
    const float r2 = rp[0] * rp[0];
    f16x8 afr[2];
#pragma unroll
    for (int ks = 0; ks < 2; ++ks)
      afr[ks] = *(const f16x8*)&HAf[(wave * 16 + c0) * 72 + ks * 32 + qd * 8];
    for (int nt = 0; nt < 4; ++nt) {
      f32x4 acc = {0.f, 0.f, 0.f, 0.f};
#pragma unroll
      for (int ks = 0; ks < 2; ++ks) {
        f16x8 bfr = *(const f16x8*)&HAf[(nt * 16 + c0) * 72 + ks * 32 + qd * 8];
        acc = __builtin_amdgcn_mfma_f32_16x16x32_f16(afr[ks], bfr, acc, 0, 0, 0);
      }
#pragma unroll
      for (int q = 0; q < 4; ++q) {
        int m1 = wave * 16 + qd * 4 + q;
        int m2 = nt * 16 + c0;
        cov_g[b * (MOBS * MOBS) + m1 * MOBS + m2] =
            acc[q] * (1.f / 63.f) + (m1 == m2 ? r2 : 0.f);
      }
    }
  }
}

// ---------------- K5: LDL^T solve (P sol = y - hxi) + T = HA^T sol ---------
__global__ __launch_bounds__(256)
void k_solve(const float* __restrict__ hxi_g, const float* __restrict__ hx_g,
             const float* __restrict__ P_g, const float* __restrict__ y,
             float* __restrict__ T_g) {
  __shared__ float Pm[64 * 65];
  __shared__ float R[64 * 64];
  __shared__ float dinv[64];
  __shared__ __align__(16) f16 HAT[64 * 72];   // [j'][m]
  __shared__ __align__(16) f16 solT[64 * 72];  // [j][m]
  const int tid = threadIdx.x;
  const int b = blockIdx.x;
  const int n = tid & 63, mg = tid >> 6;
  const int c0 = n & 15, qd = (tid & 63) >> 4;
  const int wave = tid >> 6;

  for (int idx = tid; idx < 4096; idx += 256) {
    int m = idx >> 6, j = idx & 63;
    Pm[m * 65 + j] = P_g[b * 4096 + idx];
    float hv = hxi_g[b * 4096 + idx];
    R[idx] = y[b * 64 + m] - hv;
    HAT[j * 72 + m] = (f16)(hv - hx_g[b * 64 + m]);
  }
  __syncthreads();
  // LDL^T (raw columns kept; L[m][k] = Pm[m][k]/d_k)
  for (int k = 0; k < 64; ++k) {
    float dk = Pm[k * 65 + k];
    if (n > k) {
      float f = Pm[n * 65 + k] * __builtin_amdgcn_rcpf(dk);
      for (int m = k + 1 + mg; m < 64; m += 4)
        Pm[m * 65 + n] -= Pm[m * 65 + k] * f;
    }
    __syncthreads();
  }
  if (tid < 64) dinv[tid] = __builtin_amdgcn_rcpf(Pm[tid * 65 + tid]);
  __syncthreads();
  // forward: unit-L
  for (int i = 0; i < 64; ++i) {
    float ri = R[i * 64 + n];
    float di = dinv[i];
    for (int m = i + 1 + mg; m < 64; m += 4)
      R[m * 64 + n] -= Pm[m * 65 + i] * di * ri;
    __syncthreads();
  }
  for (int idx = tid; idx < 4096; idx += 256) R[idx] *= dinv[idx >> 6];
  __syncthreads();
  // backward: L^T
  for (int i = 63; i >= 1; --i) {
    float ri = R[i * 64 + n];
    for (int m = mg; m < i; m += 4)
      R[m * 64 + n] -= Pm[i * 65 + m] * dinv[m] * ri;
    __syncthreads();
  }
  for (int idx = tid; idx < 4096; idx += 256) {
    int m = idx >> 6, j = idx & 63;
    solT[j * 72 + m] = (f16)R[m * 64 + j];
  }
  __syncthreads();
  // T[j'][j] = sum_m HA[m][j'] sol[m][j]
  {
    f16x8 afr[2];
#pragma unroll
    for (int ks = 0; ks < 2; ++ks)
      afr[ks] = *(const f16x8*)&HAT[(wave * 16 + c0) * 72 + ks * 32 + qd * 8];
    for (int nt = 0; nt < 4; ++nt) {
      f32x4 acc = {0.f, 0.f, 0.f, 0.f};
#pragma unroll
      for (int ks = 0; ks < 2; ++ks) {
        f16x8 bfr = *(const f16x8*)&solT[(nt * 16 + c0) * 72 + ks * 32 + qd * 8];
        acc = __builtin_amdgcn_mfma_f32_16x16x32_f16(afr[ks], bfr, acc, 0, 0, 0);
      }
#pragma unroll
      for (int q = 0; q < 4; ++q) {
        int jp = wave * 16 + qd * 4 + q;
        int j = nt * 16 + c0;
        T_g[b * 4096 + jp * 64 + j] = acc[q];
      }
    }
  }
}

// ---------------- K6: state_new = stateF + A @ (T/63) ----------------------
__global__ __launch_bounds__(256)
void k_update(const float* __restrict__ stateF, const float* __restrict__ T_g,
              float* __restrict__ state_out) {
  __shared__ __align__(16) f16 Af[256 * 72];  // anomaly [nh][j']
  __shared__ __align__(16) f16 TT[64 * 72];   // [j][j'] (scaled 1/63)
  __shared__ float srm[256];
  const int tid = threadIdx.x;
  const int b = blockIdx.x;
  const int lane = tid & 63, wave = tid >> 6;
  const int c0 = lane & 15, qd = lane >> 4;

  for (int idx = tid; idx < 4096; idx += 256) {
    int jp = idx >> 6, j = idx & 63;
    TT[j * 72 + jp] = (f16)(T_g[b * 4096 + idx] * (1.f / 63.f));
  }
  for (int idx = tid; idx < NH * NE; idx += 256) {
    int nh = idx >> 6, j = idx & 63;
    Af[nh * 72 + j] = (f16)stateF[b * (NH * NE) + idx];
  }
  __syncthreads();
  {
    float s = 0.f;
    for (int j = 0; j < 64; ++j) s += (float)Af[tid * 72 + j];
    srm[tid] = s * (1.f / 64.f);
  }
  __syncthreads();
  for (int idx = tid; idx < NH * NE; idx += 256) {
    int nh = idx >> 6, j = idx & 63;
    Af[nh * 72 + j] = (f16)((float)Af[nh * 72 + j] - srm[nh]);
  }
  __syncthreads();
  f16x8 bfr[4][2];
#pragma unroll
  for (int nt = 0; nt < 4; ++nt)
#pragma unroll
    for (int ks = 0; ks < 2; ++ks)
      bfr[nt][ks] = *(const f16x8*)&TT[(nt * 16 + c0) * 72 + ks * 32 + qd * 8];
  for (int mt0 = 0; mt0 < 4; ++mt0) {
    int mt = wave * 4 + mt0;
    f16x8 afr[2];
#pragma unroll
    for (int ks = 0; ks < 2; ++ks)
      afr[ks] = *(const f16x8*)&Af[(mt * 16 + c0) * 72 + ks * 32 + qd * 8];
#pragma unroll
    for (int nt = 0; nt < 4; ++nt) {
      f32x4 acc = {0.f, 0.f, 0.f, 0.f};
#pragma unroll
      for (int ks = 0; ks < 2; ++ks)
        acc = __builtin_amdgcn_mfma_f32_16x16x32_f16(afr[ks], bfr[nt][ks], acc, 0, 0, 0);
#pragma unroll
      for (int q = 0; q < 4; ++q) {
        int m = mt * 16 + qd * 4 + q;
        int j = nt * 16 + c0;
        int idx = b * (NH * NE) + m * 64 + j;
        state_out[idx] = stateF[idx] + acc[q];
      }
    }
  }
}

// ---------------- K7: per-batch loglik pieces (quad, logdet) ---------------
__global__ __launch_bounds__(256)
void k_loglik(const float* __restrict__ mu_g, const float* __restrict__ sig_g,
              const float* __restrict__ y, float* __restrict__ quad_g,
              float* __restrict__ logdet_g) {
  __shared__ float Pm[64 * 65];
  __shared__ float rv[64];
  __shared__ float r0[64];
  __shared__ float dinv[64];
  __shared__ float red[64];
  const int tid = threadIdx.x;
  const int b = blockIdx.x;
  const int n = tid & 63, mg = tid >> 6;
  for (int idx = tid; idx < 4096; idx += 256) {
    int m = idx >> 6, j = idx & 63;
    Pm[m * 65 + j] = sig_g[b * 4096 + idx] + (m == j ? 1e-6f : 0.f);
  }
  if (tid < 64) {
    float v = y[b * 64 + tid] - mu_g[b * 64 + tid];
    rv[tid] = v; r0[tid] = v;
  }
  __syncthreads();
  for (int k = 0; k < 64; ++k) {
    float dk = Pm[k * 65 + k];
    if (n > k) {
      float f = Pm[n * 65 + k] * __builtin_amdgcn_rcpf(dk);
      for (int m = k + 1 + mg; m < 64; m += 4)
        Pm[m * 65 + n] -= Pm[m * 65 + k] * f;
    }
    __syncthreads();
  }
  if (tid < 64) dinv[tid] = __builtin_amdgcn_rcpf(Pm[tid * 65 + tid]);
  __syncthreads();
  for (int i = 0; i < 64; ++i) {
    if (tid > i && tid < 64) rv[tid] -= Pm[tid * 65 + i] * dinv[i] * rv[i];
    __syncthreads();
  }
  if (tid < 64) rv[tid] *= dinv[tid];
  __syncthreads();
  for (int i = 63; i >= 1; --i) {
    if (tid < i) rv[tid] -= Pm[i * 65 + tid] * dinv[tid] * rv[i];
    __syncthreads();
  }
  if (tid < 64) red[tid] = r0[tid] * rv[tid];
  __syncthreads();
  if (tid == 0) {
    float q = 0.f, ld = 0.f;
    for (int m = 0; m < 64; ++m) { q += red[m]; ld += __logf(Pm[m * 65 + m]); }
    quad_g[b] = q;
    logdet_g[b] = ld;
  }
}

// ---------------- K8: final reduction (l, nis) -----------------------------
__global__ __launch_bounds__(64)
void k_reduce(const float* __restrict__ quad_g, const float* __restrict__ logdet_g,
              float* __restrict__ out_l, float* __restrict__ out_nis) {
  if (threadIdx.x == 0 && blockIdx.x == 0) {
    float l = 0.f, qs = 0.f;
    for (int b2 = 0; b2 < 32; ++b2) {
      l += -0.5f * (logdet_g[b2] + quad_g[b2]);
      qs += quad_g[b2];
    }
    out_l[0] = l;
    out_nis[0] = qs * (1.f / 32.f);
  }
}

extern "C" void kernel_launch(void* const* d_in, const int* in_sizes, int n_in,
                              void* d_out, int out_size, void* d_ws, size_t ws_size,
                              hipStream_t stream) {
  (void)in_sizes; (void)n_in; (void)out_size; (void)ws_size;
  const float* x     = (const float*)d_in[0];
  const float* y     = (const float*)d_in[1];
  const float* enkf  = (const float*)d_in[2];
  const float* W_ih  = (const float*)d_in[3];
  const float* W_hh  = (const float*)d_in[4];
  const float* bvec  = (const float*)d_in[5];
  const float* Wh    = (const float*)d_in[6];
  const float* bh    = (const float*)d_in[7];
  const float* qp    = (const float*)d_in[8];
  const float* ep    = (const float*)d_in[9];
  const float* rp    = (const float*)d_in[10];
  const float* eps_h = (const float*)d_in[11];
  const float* eps_c = (const float*)d_in[12];

  char* ws = (char*)d_ws;
  float* xWb    = (float*)(ws);                 // 8,388,608 B
  f16*   WhhT   = (f16*)(ws + 8388608);         //   524,288 B
  f16*   Whf    = (f16*)(ws + 8912896);         //    32,768 B
  float* stateF = (float*)(ws + 8945664);       // 2,097,152 B
  float* hxi    = (float*)(ws + 11042816);      //   524,288 B
  float* hx     = (float*)(ws + 11567104);      //     8,192 B
  float* Pg     = (float*)(ws + 11575296);      //   524,288 B
  float* Tg     = (float*)(ws + 12099584);      //   524,288 B
  float* quadg  = (float*)(ws + 12623872);      //       128 B
  float* ldg    = (float*)(ws + 12624000);      //       128 B

  float* out = (float*)d_out;
  float* mu_out    = out;           // 2048
  float* sig_out   = out + 2048;    // 131072
  float* state_out = out + 133120;  // 524288
  float* l_out     = out + 657408;
  float* nis_out   = out + 657409;

  k_xw<<<256, 256, 0, stream>>>(x, W_ih, bvec, xWb);
  k_pack<<<1088, 256, 0, stream>>>(W_hh, Wh, WhhT, Whf);
  k_lstm<<<64, 256, 0, stream>>>(xWb, WhhT, enkf, eps_h, eps_c, qp, ep, stateF);
  k_obscov<<<32, 256, 0, stream>>>(stateF, Whf, bh, rp, hxi, hx, Pg, 1);
  k_solve<<<32, 256, 0, stream>>>(hxi, hx, Pg, y, Tg);
  k_update<<<32, 256, 0, stream>>>(stateF, Tg, state_out);
  k_obscov<<<32, 256, 0, stream>>>(state_out, Whf, bh, rp, hxi, mu_out, sig_out, 0);
  k_loglik<<<32, 256, 0, stream>>>(mu_out, sig_out, y, quadg, ldg);
  k_reduce<<<1, 64, 0, stream>>>(quadg, ldg, l_out, nis_out);
}

// Round 2
// 934.112 us; speedup vs baseline: 1.7219x; 1.7219x over previous
//
#include <hip/hip_runtime.h>
#include <hip/hip_bf16.h>

// EnKF-LSTM (LS=1, BS=32, NH=256, NE=64, SEQ=64, DIN=256, MOBS=64)
// R1: k_lstm restructured — 512 thr/block (2 waves/SIMD), in-register
// elementwise (no gates LDS), B prefetch double-buffer, xWb packed float4.

typedef _Float16 f16;
typedef _Float16 f16x8 __attribute__((ext_vector_type(8)));
typedef float f32x4 __attribute__((ext_vector_type(4)));

#define BS   32
#define NH   256
#define NE   64
#define SEQQ 64
#define DIN  256
#define MOBS 64
#define G4   1024

__device__ __forceinline__ float fast_sigmoid(float x) {
  return __builtin_amdgcn_rcpf(1.f + __expf(-x));
}
__device__ __forceinline__ float fast_tanh(float x) {
  return 2.f * __builtin_amdgcn_rcpf(1.f + __expf(-2.f * x)) - 1.f;
}

// ---------------- K1: xWb4[m][j] = float4{i,f,g,o}(x @ W_ih + b) -----------
// m = b*64 + t (2048 rows), j = hidden col (256).
__global__ __launch_bounds__(256)
void k_xw(const float* __restrict__ x, const float* __restrict__ W_ih,
          const float* __restrict__ bv, float4* __restrict__ xWb4) {
  __shared__ float xs[8][DIN];
  const int tid = threadIdx.x;
  const int m0 = blockIdx.x * 8;  // 256 blocks x 8 rows
  for (int idx = tid; idx < 8 * DIN; idx += 256)
    xs[idx >> 8][idx & 255] = x[m0 * DIN + idx];
  __syncthreads();
  float acc[8][4];
#pragma unroll
  for (int r = 0; r < 8; ++r)
#pragma unroll
    for (int j = 0; j < 4; ++j) acc[r][j] = 0.f;
  for (int k = 0; k < DIN; ++k) {
    float w0 = W_ih[k * G4 + tid];
    float w1 = W_ih[k * G4 + 256 + tid];
    float w2 = W_ih[k * G4 + 512 + tid];
    float w3 = W_ih[k * G4 + 768 + tid];
#pragma unroll
    for (int r = 0; r < 8; ++r) {
      float xv = xs[r][k];
      acc[r][0] += xv * w0; acc[r][1] += xv * w1;
      acc[r][2] += xv * w2; acc[r][3] += xv * w3;
    }
  }
  const float b0v = bv[tid], b1v = bv[256 + tid], b2v = bv[512 + tid], b3v = bv[768 + tid];
#pragma unroll
  for (int r = 0; r < 8; ++r) {
    float4 v = {acc[r][0] + b0v, acc[r][1] + b1v, acc[r][2] + b2v, acc[r][3] + b3v};
    xWb4[(size_t)(m0 + r) * 256 + tid] = v;
  }
}

// ---------------- K2: pack W_hh^T (f16, [1024][256]) + Wh (f16) ------------
__global__ __launch_bounds__(256)
void k_pack(const float* __restrict__ W_hh, const float* __restrict__ Wh,
            f16* __restrict__ WhhT, f16* __restrict__ Whf) {
  int idx = blockIdx.x * 256 + threadIdx.x;
  if (idx < G4 * DIN) {
    int n = idx >> 8, k = idx & 255;
    WhhT[idx] = (f16)W_hh[k * G4 + n];
  } else {
    int i2 = idx - G4 * DIN;
    if (i2 < MOBS * NH) Whf[i2] = (f16)Wh[i2];
  }
}

// ---------------- K3: LSTM recurrence (f16 MFMA, in-register gates) --------
// 64 blocks: (member e, 16 batch rows). 8 waves: wave w owns hidden cols
// [w*32, w*32+32) for ALL 4 gates -> i,f,g,o meet in the same lane's C regs.
__global__ __launch_bounds__(512, 2)
void k_lstm(const float4* __restrict__ xWb4, const f16* __restrict__ WhhT,
            const float* __restrict__ enkf, const float* __restrict__ eps_h,
            const float* __restrict__ eps_c, const float* __restrict__ qp,
            const float* __restrict__ ep, float* __restrict__ stateF) {
  __shared__ __align__(16) f16 hs[2][16 * 264];  // [buf][row][k], pad 8
  const int tid = threadIdx.x;
  const int e = blockIdx.x >> 1;
  const int b0 = (blockIdx.x & 1) * 16;
  const int lane = tid & 63;
  const int w = tid >> 6;          // wave 0..7
  const int c0 = lane & 15;        // A row / B col / C col
  const int qd = lane >> 4;        // quad
  const int w0 = w * 32;           // hidden col base

  // init: h -> hs[0] (cooperative), c -> creg (ownership layout)
  for (int idx = tid; idx < 16 * 256; idx += 512) {
    int r = idx >> 8, n = idx & 255;
    hs[0][r * 264 + n] = (f16)enkf[((b0 + r) * NH + n) * NE + e];
  }
  float creg[2][4];
#pragma unroll
  for (int nt = 0; nt < 2; ++nt)
#pragma unroll
    for (int q = 0; q < 4; ++q)
      creg[nt][q] = enkf[((b0 + qd * 4 + q) * NH + (w0 + nt * 16 + c0)) * NE + 32 + e];
  __syncthreads();

  const float nq = fabsf(qp[0]);
  const float nee = fabsf(ep[0]);
  const f16* wbase = WhhT + qd * 8;

  for (int t = 0; t < SEQQ; ++t) {
    const f16* hcur = hs[t & 1];
    f16* hnxt = hs[(t + 1) & 1];

    // prefetch xW gate bias: 8 float4 (i,f,g,o for each owned (r,j))
    float4 xwreg[8];
#pragma unroll
    for (int nt = 0; nt < 2; ++nt)
#pragma unroll
      for (int q = 0; q < 4; ++q)
        xwreg[nt * 4 + q] =
            xWb4[((size_t)(b0 + qd * 4 + q) * 64 + t) * 256 + (w0 + nt * 16 + c0)];

    // A-fragments (shared across all 8 tiles)
    f16x8 afr[8];
#pragma unroll
    for (int ks = 0; ks < 8; ++ks)
      afr[ks] = *(const f16x8*)&hcur[c0 * 264 + ks * 32 + qd * 8];

    // 8 gate tiles: tt = g*2 + nt ; col base = g*256 + w0 + nt*16
    f32x4 acc[8];
    f16x8 bf[2][8];
    {
      const f16* p = wbase + (size_t)(w0 + c0) * 256;  // tt=0: g=0,nt=0
#pragma unroll
      for (int ks = 0; ks < 8; ++ks) bf[0][ks] = *(const f16x8*)(p + ks * 32);
    }
#pragma unroll
    for (int tt = 0; tt < 8; ++tt) {
      if (tt < 7) {
        const int t2 = tt + 1;
        const f16* p = wbase + (size_t)(((t2 >> 1) << 8) + w0 + ((t2 & 1) << 4) + c0) * 256;
#pragma unroll
        for (int ks = 0; ks < 8; ++ks)
          bf[(tt + 1) & 1][ks] = *(const f16x8*)(p + ks * 32);
      }
      f32x4 a0 = {0.f, 0.f, 0.f, 0.f}, a1 = {0.f, 0.f, 0.f, 0.f};
#pragma unroll
      for (int ks = 0; ks < 8; ks += 2) {
        a0 = __builtin_amdgcn_mfma_f32_16x16x32_f16(afr[ks], bf[tt & 1][ks], a0, 0, 0, 0);
        a1 = __builtin_amdgcn_mfma_f32_16x16x32_f16(afr[ks + 1], bf[tt & 1][ks + 1], a1, 0, 0, 0);
      }
      acc[tt] = a0 + a1;
    }

    // elementwise in registers
    const bool last = (t == SEQQ - 1);
#pragma unroll
    for (int nt = 0; nt < 2; ++nt) {
      const int j = w0 + nt * 16 + c0;
#pragma unroll
      for (int q = 0; q < 4; ++q) {
        const int r = qd * 4 + q;
        float4 xw = xwreg[nt * 4 + q];
        float iv = acc[0 * 2 + nt][q] + xw.x;
        float fv = acc[1 * 2 + nt][q] + xw.y;
        float gv = acc[2 * 2 + nt][q] + xw.z;
        float ov = acc[3 * 2 + nt][q] + xw.w;
        float c2 = fast_sigmoid(fv) * creg[nt][q] + fast_sigmoid(iv) * fast_tanh(gv);
        float h2 = fast_sigmoid(ov) * fast_tanh(c2);
        creg[nt][q] = c2;
        hnxt[r * 264 + j] = (f16)h2;
        if (last) {
          stateF[((b0 + r) * NH + j) * NE + e] =
              h2 + nq * eps_h[(e * BS + b0 + r) * NH + j];
          stateF[((b0 + r) * NH + j) * NE + 32 + e] =
              c2 + nee * eps_c[(e * BS + b0 + r) * NH + j];
        }
      }
    }
    __syncthreads();
  }
}

// ---------------- K4: obs + mean + cov (per batch) -------------------------
__global__ __launch_bounds__(256)
void k_obscov(const float* __restrict__ state, const f16* __restrict__ Whf,
              const float* __restrict__ bh, const float* __restrict__ rp,
              float* __restrict__ hxi_g, float* __restrict__ mean_g,
              float* __restrict__ cov_g, int write_hxi) {
  __shared__ __align__(16) f16 stT[64 * 264];   // [j][k=nh]
  __shared__ float hxl[64 * 66];
  __shared__ float hxm[64];
  __shared__ __align__(16) f16 HAf[64 * 72];    // [m][j]
  const int tid = threadIdx.x;
  const int b = blockIdx.x;
  const int lane = tid & 63, wave = tid >> 6;
  const int c0 = lane & 15, qd = lane >> 4;

  for (int idx = tid; idx < NH * NE; idx += 256) {
    int k = idx >> 6, j = idx & 63;
    stT[j * 264 + k] = (f16)state[b * (NH * NE) + idx];
  }
  __syncthreads();
  {
    f16x8 afr[8];
#pragma unroll
    for (int ks = 0; ks < 8; ++ks)
      afr[ks] = *(const f16x8*)&Whf[(wave * 16 + c0) * DIN + ks * 32 + qd * 8];
    for (int nt = 0; nt < 4; ++nt) {
      f32x4 acc = {0.f, 0.f, 0.f, 0.f};
#pragma unroll
      for (int ks = 0; ks < 8; ++ks) {
        f16x8 bfr = *(const f16x8*)&stT[(nt * 16 + c0) * 264 + ks * 32 + qd * 8];
        acc = __builtin_amdgcn_mfma_f32_16x16x32_f16(afr[ks], bfr, acc, 0, 0, 0);
      }
#pragma unroll
      for (int q = 0; q < 4; ++q) {
        int m = wave * 16 + qd * 4 + q;
        int j = nt * 16 + c0;
        float v = acc[q] + bh[m];
        hxl[m * 66 + j] = v;
        if (write_hxi) hxi_g[b * (MOBS * NE) + m * NE + j] = v;
      }
    }
  }
  __syncthreads();
  if (tid < 64) {
    float s = 0.f;
    for (int j = 0; j < 64; ++j) s += hxl[tid * 66 + j];
    s *= (1.f / 64.f);
    hxm[tid] = s;
    mean_g[b * MOBS + tid] = s;
  }
  __syncthreads();
  for (int idx = tid; idx < 64 * 64; idx += 256) {
    int m = idx >> 6, j = idx & 63;
    HAf[m * 72 + j] = (f16)(hxl[m * 66 + j] - hxm[m]);
  }
  __syncthreads();
  {
    const float r2 = rp[0] * rp[0];
    f16x8 afr[2];
#pragma unroll
    for (int ks = 0; ks < 2; ++ks)
      afr[ks] = *(const f16x8*)&HAf[(wave * 16 + c0) * 72 + ks * 32 + qd * 8];
    for (int nt = 0; nt < 4; ++nt) {
      f32x4 acc = {0.f, 0.f, 0.f, 0.f};
#pragma unroll
      for (int ks = 0; ks < 2; ++ks) {
        f16x8 bfr = *(const f16x8*)&HAf[(nt * 16 + c0) * 72 + ks * 32 + qd * 8];
        acc = __builtin_amdgcn_mfma_f32_16x16x32_f16(afr[ks], bfr, acc, 0, 0, 0);
      }
#pragma unroll
      for (int q = 0; q < 4; ++q) {
        int m1 = wave * 16 + qd * 4 + q;
        int m2 = nt * 16 + c0;
        cov_g[b * (MOBS * MOBS) + m1 * MOBS + m2] =
            acc[q] * (1.f / 63.f) + (m1 == m2 ? r2 : 0.f);
      }
    }
  }
}

// ---------------- K5: LDL^T solve (P sol = y - hxi) + T = HA^T sol ---------
__global__ __launch_bounds__(256)
void k_solve(const float* __restrict__ hxi_g, const float* __restrict__ hx_g,
             const float* __restrict__ P_g, const float* __restrict__ y,
             float* __restrict__ T_g) {
  __shared__ float Pm[64 * 65];
  __shared__ float R[64 * 64];
  __shared__ float dinv[64];
  __shared__ __align__(16) f16 HAT[64 * 72];   // [j'][m]
  __shared__ __align__(16) f16 solT[64 * 72];  // [j][m]
  const int tid = threadIdx.x;
  const int b = blockIdx.x;
  const int n = tid & 63, mg = tid >> 6;
  const int c0 = n & 15, qd = (tid & 63) >> 4;
  const int wave = tid >> 6;

  for (int idx = tid; idx < 4096; idx += 256) {
    int m = idx >> 6, j = idx & 63;
    Pm[m * 65 + j] = P_g[b * 4096 + idx];
    float hv = hxi_g[b * 4096 + idx];
    R[idx] = y[b * 64 + m] - hv;
    HAT[j * 72 + m] = (f16)(hv - hx_g[b * 64 + m]);
  }
  __syncthreads();
  for (int k = 0; k < 64; ++k) {
    float dk = Pm[k * 65 + k];
    if (n > k) {
      float f = Pm[n * 65 + k] * __builtin_amdgcn_rcpf(dk);
      for (int m = k + 1 + mg; m < 64; m += 4)
        Pm[m * 65 + n] -= Pm[m * 65 + k] * f;
    }
    __syncthreads();
  }
  if (tid < 64) dinv[tid] = __builtin_amdgcn_rcpf(Pm[tid * 65 + tid]);
  __syncthreads();
  for (int i = 0; i < 64; ++i) {
    float ri = R[i * 64 + n];
    float di = dinv[i];
    for (int m = i + 1 + mg; m < 64; m += 4)
      R[m * 64 + n] -= Pm[m * 65 + i] * di * ri;
    __syncthreads();
  }
  for (int idx = tid; idx < 4096; idx += 256) R[idx] *= dinv[idx >> 6];
  __syncthreads();
  for (int i = 63; i >= 1; --i) {
    float ri = R[i * 64 + n];
    for (int m = mg; m < i; m += 4)
      R[m * 64 + n] -= Pm[i * 65 + m] * dinv[m] * ri;
    __syncthreads();
  }
  for (int idx = tid; idx < 4096; idx += 256) {
    int m = idx >> 6, j = idx & 63;
    solT[j * 72 + m] = (f16)R[m * 64 + j];
  }
  __syncthreads();
  {
    f16x8 afr[2];
#pragma unroll
    for (int ks = 0; ks < 2; ++ks)
      afr[ks] = *(const f16x8*)&HAT[(wave * 16 + c0) * 72 + ks * 32 + qd * 8];
    for (int nt = 0; nt < 4; ++nt) {
      f32x4 acc = {0.f, 0.f, 0.f, 0.f};
#pragma unroll
      for (int ks = 0; ks < 2; ++ks) {
        f16x8 bfr = *(const f16x8*)&solT[(nt * 16 + c0) * 72 + ks * 32 + qd * 8];
        acc = __builtin_amdgcn_mfma_f32_16x16x32_f16(afr[ks], bfr, acc, 0, 0, 0);
      }
#pragma unroll
      for (int q = 0; q < 4; ++q) {
        int jp = wave * 16 + qd * 4 + q;
        int j = nt * 16 + c0;
        T_g[b * 4096 + jp * 64 + j] = acc[q];
      }
    }
  }
}

// ---------------- K6: state_new = stateF + A @ (T/63) ----------------------
__global__ __launch_bounds__(256)
void k_update(const float* __restrict__ stateF, const float* __restrict__ T_g,
              float* __restrict__ state_out) {
  __shared__ __align__(16) f16 Af[256 * 72];  // anomaly [nh][j']
  __shared__ __align__(16) f16 TT[64 * 72];   // [j][j'] (scaled 1/63)
  __shared__ float srm[256];
  const int tid = threadIdx.x;
  const int b = blockIdx.x;
  const int lane = tid & 63, wave = tid >> 6;
  const int c0 = lane & 15, qd = lane >> 4;

  for (int idx = tid; idx < 4096; idx += 256) {
    int jp = idx >> 6, j = idx & 63;
    TT[j * 72 + jp] = (f16)(T_g[b * 4096 + idx] * (1.f / 63.f));
  }
  for (int idx = tid; idx < NH * NE; idx += 256) {
    int nh = idx >> 6, j = idx & 63;
    Af[nh * 72 + j] = (f16)stateF[b * (NH * NE) + idx];
  }
  __syncthreads();
  {
    float s = 0.f;
    for (int j = 0; j < 64; ++j) s += (float)Af[tid * 72 + j];
    srm[tid] = s * (1.f / 64.f);
  }
  __syncthreads();
  for (int idx = tid; idx < NH * NE; idx += 256) {
    int nh = idx >> 6, j = idx & 63;
    Af[nh * 72 + j] = (f16)((float)Af[nh * 72 + j] - srm[nh]);
  }
  __syncthreads();
  f16x8 bfr[4][2];
#pragma unroll
  for (int nt = 0; nt < 4; ++nt)
#pragma unroll
    for (int ks = 0; ks < 2; ++ks)
      bfr[nt][ks] = *(const f16x8*)&TT[(nt * 16 + c0) * 72 + ks * 32 + qd * 8];
  for (int mt0 = 0; mt0 < 4; ++mt0) {
    int mt = wave * 4 + mt0;
    f16x8 afr[2];
#pragma unroll
    for (int ks = 0; ks < 2; ++ks)
      afr[ks] = *(const f16x8*)&Af[(mt * 16 + c0) * 72 + ks * 32 + qd * 8];
#pragma unroll
    for (int nt = 0; nt < 4; ++nt) {
      f32x4 acc = {0.f, 0.f, 0.f, 0.f};
#pragma unroll
      for (int ks = 0; ks < 2; ++ks)
        acc = __builtin_amdgcn_mfma_f32_16x16x32_f16(afr[ks], bfr[nt][ks], acc, 0, 0, 0);
#pragma unroll
      for (int q = 0; q < 4; ++q) {
        int m = mt * 16 + qd * 4 + q;
        int j = nt * 16 + c0;
        int idx = b * (NH * NE) + m * 64 + j;
        state_out[idx] = stateF[idx] + acc[q];
      }
    }
  }
}

// ---------------- K7: per-batch loglik pieces (quad, logdet) ---------------
__global__ __launch_bounds__(256)
void k_loglik(const float* __restrict__ mu_g, const float* __restrict__ sig_g,
              const float* __restrict__ y, float* __restrict__ quad_g,
              float* __restrict__ logdet_g) {
  __shared__ float Pm[64 * 65];
  __shared__ float rv[64];
  __shared__ float r0[64];
  __shared__ float dinv[64];
  __shared__ float red[64];
  const int tid = threadIdx.x;
  const int b = blockIdx.x;
  const int n = tid & 63, mg = tid >> 6;
  for (int idx = tid; idx < 4096; idx += 256) {
    int m = idx >> 6, j = idx & 63;
    Pm[m * 65 + j] = sig_g[b * 4096 + idx] + (m == j ? 1e-6f : 0.f);
  }
  if (tid < 64) {
    float v = y[b * 64 + tid] - mu_g[b * 64 + tid];
    rv[tid] = v; r0[tid] = v;
  }
  __syncthreads();
  for (int k = 0; k < 64; ++k) {
    float dk = Pm[k * 65 + k];
    if (n > k) {
      float f = Pm[n * 65 + k] * __builtin_amdgcn_rcpf(dk);
      for (int m = k + 1 + mg; m < 64; m += 4)
        Pm[m * 65 + n] -= Pm[m * 65 + k] * f;
    }
    __syncthreads();
  }
  if (tid < 64) dinv[tid] = __builtin_amdgcn_rcpf(Pm[tid * 65 + tid]);
  __syncthreads();
  for (int i = 0; i < 64; ++i) {
    if (tid > i && tid < 64) rv[tid] -= Pm[tid * 65 + i] * dinv[i] * rv[i];
    __syncthreads();
  }
  if (tid < 64) rv[tid] *= dinv[tid];
  __syncthreads();
  for (int i = 63; i >= 1; --i) {
    if (tid < i) rv[tid] -= Pm[i * 65 + tid] * dinv[tid] * rv[i];
    __syncthreads();
  }
  if (tid < 64) red[tid] = r0[tid] * rv[tid];
  __syncthreads();
  if (tid == 0) {
    float q = 0.f, ld = 0.f;
    for (int m = 0; m < 64; ++m) { q += red[m]; ld += __logf(Pm[m * 65 + m]); }
    quad_g[b] = q;
    logdet_g[b] = ld;
  }
}

// ---------------- K8: final reduction (l, nis) -----------------------------
__global__ __launch_bounds__(64)
void k_reduce(const float* __restrict__ quad_g, const float* __restrict__ logdet_g,
              float* __restrict__ out_l, float* __restrict__ out_nis) {
  if (threadIdx.x == 0 && blockIdx.x == 0) {
    float l = 0.f, qs = 0.f;
    for (int b2 = 0; b2 < 32; ++b2) {
      l += -0.5f * (logdet_g[b2] + quad_g[b2]);
      qs += quad_g[b2];
    }
    out_l[0] = l;
    out_nis[0] = qs * (1.f / 32.f);
  }
}

extern "C" void kernel_launch(void* const* d_in, const int* in_sizes, int n_in,
                              void* d_out, int out_size, void* d_ws, size_t ws_size,
                              hipStream_t stream) {
  (void)in_sizes; (void)n_in; (void)out_size; (void)ws_size;
  const float* x     = (const float*)d_in[0];
  const float* y     = (const float*)d_in[1];
  const float* enkf  = (const float*)d_in[2];
  const float* W_ih  = (const float*)d_in[3];
  const float* W_hh  = (const float*)d_in[4];
  const float* bvec  = (const float*)d_in[5];
  const float* Wh    = (const float*)d_in[6];
  const float* bh    = (const float*)d_in[7];
  const float* qp    = (const float*)d_in[8];
  const float* ep    = (const float*)d_in[9];
  const float* rp    = (const float*)d_in[10];
  const float* eps_h = (const float*)d_in[11];
  const float* eps_c = (const float*)d_in[12];

  char* ws = (char*)d_ws;
  float4* xWb4  = (float4*)(ws);                // 8,388,608 B
  f16*   WhhT   = (f16*)(ws + 8388608);         //   524,288 B
  f16*   Whf    = (f16*)(ws + 8912896);         //    32,768 B
  float* stateF = (float*)(ws + 8945664);       // 2,097,152 B
  float* hxi    = (float*)(ws + 11042816);      //   524,288 B
  float* hx     = (float*)(ws + 11567104);      //     8,192 B
  float* Pg     = (float*)(ws + 11575296);      //   524,288 B
  float* Tg     = (float*)(ws + 12099584);      //   524,288 B
  float* quadg  = (float*)(ws + 12623872);      //       128 B
  float* ldg    = (float*)(ws + 12624000);      //       128 B

  float* out = (float*)d_out;
  float* mu_out    = out;           // 2048
  float* sig_out   = out + 2048;    // 131072
  float* state_out = out + 133120;  // 524288
  float* l_out     = out + 657408;
  float* nis_out   = out + 657409;

  k_xw<<<256, 256, 0, stream>>>(x, W_ih, bvec, xWb4);
  k_pack<<<1088, 256, 0, stream>>>(W_hh, Wh, WhhT, Whf);
  k_lstm<<<64, 512, 0, stream>>>(xWb4, WhhT, enkf, eps_h, eps_c, qp, ep, stateF);
  k_obscov<<<32, 256, 0, stream>>>(stateF, Whf, bh, rp, hxi, hx, Pg, 1);
  k_solve<<<32, 256, 0, stream>>>(hxi, hx, Pg, y, Tg);
  k_update<<<32, 256, 0, stream>>>(stateF, Tg, state_out);
  k_obscov<<<32, 256, 0, stream>>>(state_out, Whf, bh, rp, hxi, mu_out, sig_out, 0);
  k_loglik<<<32, 256, 0, stream>>>(mu_out, sig_out, y, quadg, ldg);
  k_reduce<<<1, 64, 0, stream>>>(quadg, ldg, l_out, nis_out);
}

// Round 3
// 819.187 us; speedup vs baseline: 1.9635x; 1.1403x over previous
//
#include <hip/hip_runtime.h>
#include <hip/hip_bf16.h>

// EnKF-LSTM (LS=1, BS=32, NH=256, NE=64, SEQ=64, DIN=256, MOBS=64)
// R2: fragment-packed W (coalesced B loads), cyclic cross-step prefetch,
// MFMA k_xw, fused tail kernel (obscov+solve+update+obscov+loglik in LDS).

typedef _Float16 f16;
typedef _Float16 f16x8 __attribute__((ext_vector_type(8)));
typedef float f32x4 __attribute__((ext_vector_type(4)));

#define BS   32
#define NH   256
#define NE   64
#define SEQQ 64
#define DIN  256
#define MOBS 64
#define G4   1024

__device__ __forceinline__ float fast_sigmoid(float x) {
  return __builtin_amdgcn_rcpf(1.f + __expf(-x));
}
__device__ __forceinline__ float fast_tanh(float x) {
  return 2.f * __builtin_amdgcn_rcpf(1.f + __expf(-2.f * x)) - 1.f;
}

// ---------------- K0: pack weights into MFMA fragment order ----------------
// Wpack[((tile*8+ks)*64+lane)*8+j] = W[(ks*32+(lane>>4)*8+j)*1024 + tile*16+(lane&15)]
// blocks 0..127: W_hh -> Wpack ; 128..255: W_ih -> WpackIh ; 256: Wh -> WhfP
__global__ __launch_bounds__(256)
void k_pack(const float* __restrict__ W_hh, const float* __restrict__ W_ih,
            const float* __restrict__ Wh, f16* __restrict__ Wpack,
            f16* __restrict__ WpackIh, f16* __restrict__ WhfP) {
  const int blk = blockIdx.x, tid = threadIdx.x;
  if (blk < 256) {
    const float* src = (blk < 128) ? W_hh : W_ih;
    f16* dst = (blk < 128) ? Wpack : WpackIh;
    int g = (blk & 127) * 256 + tid;  // 0..32767
    int lane = g & 63, ks = (g >> 6) & 7, tile = g >> 9;
    int k0 = ks * 32 + (lane >> 4) * 8;
    int col = tile * 16 + (lane & 15);
#pragma unroll
    for (int j = 0; j < 8; ++j)
      dst[g * 8 + j] = (f16)src[(k0 + j) * G4 + col];
  } else {
    // WhfP[((mt*8+ks)*64+lane)*8+j] = Wh[(mt*16+(lane&15))*256 + ks*32+(lane>>4)*8+j]
    for (int g = tid; g < 2048; g += 256) {
      int lane = g & 63, ks = (g >> 6) & 7, mt = g >> 9;
      int row = mt * 16 + (lane & 15);
      int k0 = ks * 32 + (lane >> 4) * 8;
#pragma unroll
      for (int j = 0; j < 8; ++j)
        WhfP[g * 8 + j] = (f16)Wh[row * NH + k0 + j];
    }
  }
}

// ---------------- K1: xWb4 = float4{i,f,g,o}(x @ W_ih + b), f16 MFMA -------
// 128 blocks x 16 rows (m = seqrow*64+t), 8 waves; wave owns cols w*32..+31.
__global__ __launch_bounds__(512, 2)
void k_xw(const float* __restrict__ x, const f16* __restrict__ WpackIh,
          const float* __restrict__ bv, float4* __restrict__ xWb4) {
  __shared__ __align__(16) f16 xs[16 * 264];
  const int tid = threadIdx.x;
  const int m0 = blockIdx.x * 16;
  const int lane = tid & 63, w = tid >> 6;
  const int c0 = lane & 15, qd = lane >> 4;
  const int w0 = w * 32;
  for (int idx = tid; idx < 16 * 256; idx += 512) {
    int r = idx >> 8, k = idx & 255;
    xs[r * 264 + k] = (f16)x[(size_t)(m0 + r) * 256 + k];
  }
  __syncthreads();
  f16x8 afr[8];
#pragma unroll
  for (int ks = 0; ks < 8; ++ks)
    afr[ks] = *(const f16x8*)&xs[c0 * 264 + ks * 32 + qd * 8];
  const f16* wp0 = WpackIh + (size_t)lane * 8;
  f32x4 acc[8];
#pragma unroll
  for (int tt = 0; tt < 8; ++tt) {
    const int tg = ((tt >> 1) << 4) + w * 2 + (tt & 1);
    const f16* p = wp0 + (size_t)tg * 4096;
    f16x8 bf[8];
#pragma unroll
    for (int ks = 0; ks < 8; ++ks) bf[ks] = *(const f16x8*)(p + ks * 512);
    f32x4 a0 = {0.f, 0.f, 0.f, 0.f}, a1 = {0.f, 0.f, 0.f, 0.f};
#pragma unroll
    for (int ks = 0; ks < 8; ks += 2) {
      a0 = __builtin_amdgcn_mfma_f32_16x16x32_f16(afr[ks], bf[ks], a0, 0, 0, 0);
      a1 = __builtin_amdgcn_mfma_f32_16x16x32_f16(afr[ks + 1], bf[ks + 1], a1, 0, 0, 0);
    }
    acc[tt] = a0 + a1;
  }
#pragma unroll
  for (int nt = 0; nt < 2; ++nt) {
    const int j = w0 + nt * 16 + c0;
#pragma unroll
    for (int q = 0; q < 4; ++q) {
      const int m = m0 + qd * 4 + q;
      float4 v = {acc[0 + nt][q] + bv[j], acc[2 + nt][q] + bv[256 + j],
                  acc[4 + nt][q] + bv[512 + j], acc[6 + nt][q] + bv[768 + j]};
      xWb4[(size_t)m * 256 + j] = v;
    }
  }
}

// ---------------- K2: LSTM recurrence (f16 MFMA, coalesced packed W) -------
__global__ __launch_bounds__(512, 2)
void k_lstm(const float4* __restrict__ xWb4, const f16* __restrict__ Wpack,
            const float* __restrict__ enkf, const float* __restrict__ eps_h,
            const float* __restrict__ eps_c, const float* __restrict__ qp,
            const float* __restrict__ ep, float* __restrict__ stateF) {
  __shared__ __align__(16) f16 hs[2][16 * 264];
  const int tid = threadIdx.x;
  const int e = blockIdx.x >> 1;
  const int b0 = (blockIdx.x & 1) * 16;
  const int lane = tid & 63;
  const int w = tid >> 6;
  const int c0 = lane & 15;
  const int qd = lane >> 4;
  const int w0 = w * 32;

  for (int idx = tid; idx < 16 * 256; idx += 512) {
    int r = idx >> 8, nh = idx & 255;
    hs[0][r * 264 + nh] = (f16)enkf[((b0 + r) * NH + nh) * NE + e];
  }
  float creg[2][4];
#pragma unroll
  for (int nt = 0; nt < 2; ++nt)
#pragma unroll
    for (int q = 0; q < 4; ++q)
      creg[nt][q] = enkf[((b0 + qd * 4 + q) * NH + (w0 + nt * 16 + c0)) * NE + 32 + e];
  __syncthreads();

  const float nq = fabsf(qp[0]);
  const float nee = fabsf(ep[0]);
  const f16* wp0 = Wpack + (size_t)lane * 8;

  // preload tile tt=0 (tg = w*2)
  f16x8 bf[2][8];
  {
    const f16* p = wp0 + (size_t)(w * 2) * 4096;
#pragma unroll
    for (int ks = 0; ks < 8; ++ks) bf[0][ks] = *(const f16x8*)(p + ks * 512);
  }

  for (int t = 0; t < SEQQ; ++t) {
    const f16* hcur = hs[t & 1];
    f16* hnxt = hs[(t + 1) & 1];

    float4 xwreg[8];
#pragma unroll
    for (int nt = 0; nt < 2; ++nt)
#pragma unroll
      for (int q = 0; q < 4; ++q)
        xwreg[nt * 4 + q] =
            xWb4[((size_t)(b0 + qd * 4 + q) * 64 + t) * 256 + (w0 + nt * 16 + c0)];

    f16x8 afr[8];
#pragma unroll
    for (int ks = 0; ks < 8; ++ks)
      afr[ks] = *(const f16x8*)&hcur[c0 * 264 + ks * 32 + qd * 8];

    f32x4 acc[8];
#pragma unroll
    for (int tt = 0; tt < 8; ++tt) {
      // cyclic prefetch: (tt+1)&7 — tile 0 of next step loads during tile 7
      const int t2 = (tt + 1) & 7;
      const f16* p = wp0 + (size_t)(((t2 >> 1) << 4) + w * 2 + (t2 & 1)) * 4096;
#pragma unroll
      for (int ks = 0; ks < 8; ++ks)
        bf[(tt + 1) & 1][ks] = *(const f16x8*)(p + ks * 512);
      f32x4 a0 = {0.f, 0.f, 0.f, 0.f}, a1 = {0.f, 0.f, 0.f, 0.f};
#pragma unroll
      for (int ks = 0; ks < 8; ks += 2) {
        a0 = __builtin_amdgcn_mfma_f32_16x16x32_f16(afr[ks], bf[tt & 1][ks], a0, 0, 0, 0);
        a1 = __builtin_amdgcn_mfma_f32_16x16x32_f16(afr[ks + 1], bf[tt & 1][ks + 1], a1, 0, 0, 0);
      }
      acc[tt] = a0 + a1;
    }

    const bool last = (t == SEQQ - 1);
#pragma unroll
    for (int nt = 0; nt < 2; ++nt) {
      const int j = w0 + nt * 16 + c0;
#pragma unroll
      for (int q = 0; q < 4; ++q) {
        const int r = qd * 4 + q;
        float4 xw = xwreg[nt * 4 + q];
        float iv = acc[0 + nt][q] + xw.x;
        float fv = acc[2 + nt][q] + xw.y;
        float gv = acc[4 + nt][q] + xw.z;
        float ov = acc[6 + nt][q] + xw.w;
        float c2 = fast_sigmoid(fv) * creg[nt][q] + fast_sigmoid(iv) * fast_tanh(gv);
        float h2 = fast_sigmoid(ov) * fast_tanh(c2);
        creg[nt][q] = c2;
        hnxt[r * 264 + j] = (f16)h2;
        if (last) {
          stateF[((b0 + r) * NH + j) * NE + e] =
              h2 + nq * eps_h[(e * BS + b0 + r) * NH + j];
          stateF[((b0 + r) * NH + j) * NE + 32 + e] =
              c2 + nee * eps_c[(e * BS + b0 + r) * NH + j];
        }
      }
    }
    __syncthreads();
  }
}

// ---------------- K3: fused tail (per-batch): obscov+solve+update+obscov+loglik
__global__ __launch_bounds__(256)
void k_fused(const float* __restrict__ stateF, const f16* __restrict__ WhfP,
             const float* __restrict__ bh, const float* __restrict__ rp,
             const float* __restrict__ y, float* __restrict__ mu_out,
             float* __restrict__ sig_out, float* __restrict__ state_out,
             float* __restrict__ quad_g, float* __restrict__ logdet_g) {
  __shared__ __align__(16) f16 stT[64 * 264];   // phase1 state^T ; phase3 new state^T
  __shared__ float hxl[64 * 66];
  __shared__ float Pm[64 * 65];
  __shared__ __align__(16) f16 TT[64 * 72];
  __shared__ __align__(16) char U[36864];       // HAf | (R,HAT,solT) | Af | HAf2
  __shared__ float hxm[64];
  __shared__ float dinv[64];
  __shared__ float srm[256];
  __shared__ float rv[64], r0v[64], red[64];

  const int tid = threadIdx.x, b = blockIdx.x;
  const int lane = tid & 63, wave = tid >> 6;
  const int c0 = lane & 15, qd = lane >> 4;
  const int n = tid & 63, mg = tid >> 6;
  const float r2 = rp[0] * rp[0];

  // Wh A-fragments (coalesced packed) — reused in phase 1 and 4
  f16x8 whfr[8];
#pragma unroll
  for (int ks = 0; ks < 8; ++ks)
    whfr[ks] = *(const f16x8*)&WhfP[(((size_t)wave * 8 + ks) * 64 + lane) * 8];

  // ---- phase 1: hxi = Wh@stateF + bh ; mean ; HA ; P = HA HA^T/63 + r^2 I
  for (int idx = tid; idx < NH * NE; idx += 256) {
    int k = idx >> 6, j = idx & 63;
    stT[j * 264 + k] = (f16)stateF[b * (NH * NE) + idx];
  }
  __syncthreads();
  for (int nt = 0; nt < 4; ++nt) {
    f32x4 acc = {0.f, 0.f, 0.f, 0.f};
#pragma unroll
    for (int ks = 0; ks < 8; ++ks) {
      f16x8 bfr = *(const f16x8*)&stT[(nt * 16 + c0) * 264 + ks * 32 + qd * 8];
      acc = __builtin_amdgcn_mfma_f32_16x16x32_f16(whfr[ks], bfr, acc, 0, 0, 0);
    }
#pragma unroll
    for (int q = 0; q < 4; ++q)
      hxl[(wave * 16 + qd * 4 + q) * 66 + nt * 16 + c0] = acc[q] + bh[wave * 16 + qd * 4 + q];
  }
  __syncthreads();
  if (tid < 64) {
    float s = 0.f;
    for (int j = 0; j < 64; ++j) s += hxl[tid * 66 + j];
    hxm[tid] = s * (1.f / 64.f);
  }
  __syncthreads();
  {
    f16* HAf = (f16*)U;
    for (int idx = tid; idx < 4096; idx += 256) {
      int m = idx >> 6, j = idx & 63;
      HAf[m * 72 + j] = (f16)(hxl[m * 66 + j] - hxm[m]);
    }
    __syncthreads();
    f16x8 afr[2];
#pragma unroll
    for (int ks = 0; ks < 2; ++ks)
      afr[ks] = *(const f16x8*)&HAf[(wave * 16 + c0) * 72 + ks * 32 + qd * 8];
    for (int nt = 0; nt < 4; ++nt) {
      f32x4 acc = {0.f, 0.f, 0.f, 0.f};
#pragma unroll
      for (int ks = 0; ks < 2; ++ks) {
        f16x8 bfr = *(const f16x8*)&HAf[(nt * 16 + c0) * 72 + ks * 32 + qd * 8];
        acc = __builtin_amdgcn_mfma_f32_16x16x32_f16(afr[ks], bfr, acc, 0, 0, 0);
      }
#pragma unroll
      for (int q = 0; q < 4; ++q) {
        int m1 = wave * 16 + qd * 4 + q, m2 = nt * 16 + c0;
        Pm[m1 * 65 + m2] = acc[q] * (1.f / 63.f) + (m1 == m2 ? r2 : 0.f);
      }
    }
  }
  __syncthreads();

  // ---- phase 2: LDL^T solve P sol = y - hxi ; T = HA^T sol (scaled -> TT)
  {
    float* R = (float*)U;
    f16* HAT = (f16*)(U + 16384);
    f16* solT = (f16*)(U + 25600);
    for (int idx = tid; idx < 4096; idx += 256) {
      int m = idx >> 6, j = idx & 63;
      float hv = hxl[m * 66 + j];
      R[idx] = y[b * 64 + m] - hv;
      HAT[j * 72 + m] = (f16)(hv - hxm[m]);
    }
    __syncthreads();
    for (int k = 0; k < 64; ++k) {
      float dk = Pm[k * 65 + k];
      if (n > k) {
        float f = Pm[n * 65 + k] * __builtin_amdgcn_rcpf(dk);
        for (int m = k + 1 + mg; m < 64; m += 4)
          Pm[m * 65 + n] -= Pm[m * 65 + k] * f;
      }
      __syncthreads();
    }
    if (tid < 64) dinv[tid] = __builtin_amdgcn_rcpf(Pm[tid * 65 + tid]);
    __syncthreads();
    for (int i = 0; i < 64; ++i) {
      float ri = R[i * 64 + n];
      float di = dinv[i];
      for (int m = i + 1 + mg; m < 64; m += 4)
        R[m * 64 + n] -= Pm[m * 65 + i] * di * ri;
      __syncthreads();
    }
    for (int idx = tid; idx < 4096; idx += 256) R[idx] *= dinv[idx >> 6];
    __syncthreads();
    for (int i = 63; i >= 1; --i) {
      float ri = R[i * 64 + n];
      for (int m = mg; m < i; m += 4)
        R[m * 64 + n] -= Pm[i * 65 + m] * dinv[m] * ri;
      __syncthreads();
    }
    for (int idx = tid; idx < 4096; idx += 256) {
      int m = idx >> 6, j = idx & 63;
      solT[j * 72 + m] = (f16)R[m * 64 + j];
    }
    __syncthreads();
    f16x8 afr[2];
#pragma unroll
    for (int ks = 0; ks < 2; ++ks)
      afr[ks] = *(const f16x8*)&HAT[(wave * 16 + c0) * 72 + ks * 32 + qd * 8];
    for (int nt = 0; nt < 4; ++nt) {
      f32x4 acc = {0.f, 0.f, 0.f, 0.f};
#pragma unroll
      for (int ks = 0; ks < 2; ++ks) {
        f16x8 bfr = *(const f16x8*)&solT[(nt * 16 + c0) * 72 + ks * 32 + qd * 8];
        acc = __builtin_amdgcn_mfma_f32_16x16x32_f16(afr[ks], bfr, acc, 0, 0, 0);
      }
#pragma unroll
      for (int q = 0; q < 4; ++q) {
        int jp = wave * 16 + qd * 4 + q, j = nt * 16 + c0;
        TT[j * 72 + jp] = (f16)(acc[q] * (1.f / 63.f));
      }
    }
  }
  __syncthreads();

  // ---- phase 3: state_out = stateF + A @ TT ; build new state^T in stT
  {
    f16* Af = (f16*)U;
    for (int idx = tid; idx < NH * NE; idx += 256) {
      int nh = idx >> 6, j = idx & 63;
      Af[nh * 72 + j] = (f16)stateF[b * (NH * NE) + idx];
    }
    __syncthreads();
    {
      float s = 0.f;
      for (int j = 0; j < 64; ++j) s += (float)Af[tid * 72 + j];
      srm[tid] = s * (1.f / 64.f);
    }
    __syncthreads();
    for (int idx = tid; idx < NH * NE; idx += 256) {
      int nh = idx >> 6, j = idx & 63;
      Af[nh * 72 + j] = (f16)((float)Af[nh * 72 + j] - srm[nh]);
    }
    __syncthreads();
    f16x8 bfr[4][2];
#pragma unroll
    for (int nt = 0; nt < 4; ++nt)
#pragma unroll
      for (int ks = 0; ks < 2; ++ks)
        bfr[nt][ks] = *(const f16x8*)&TT[(nt * 16 + c0) * 72 + ks * 32 + qd * 8];
    for (int mt0 = 0; mt0 < 4; ++mt0) {
      int mt = wave * 4 + mt0;
      f16x8 afr[2];
#pragma unroll
      for (int ks = 0; ks < 2; ++ks)
        afr[ks] = *(const f16x8*)&Af[(mt * 16 + c0) * 72 + ks * 32 + qd * 8];
#pragma unroll
      for (int nt = 0; nt < 4; ++nt) {
        f32x4 acc = {0.f, 0.f, 0.f, 0.f};
#pragma unroll
        for (int ks = 0; ks < 2; ++ks)
          acc = __builtin_amdgcn_mfma_f32_16x16x32_f16(afr[ks], bfr[nt][ks], acc, 0, 0, 0);
#pragma unroll
        for (int q = 0; q < 4; ++q) {
          int m = mt * 16 + qd * 4 + q, j = nt * 16 + c0;
          int idx = b * (NH * NE) + m * 64 + j;
          float v = stateF[idx] + acc[q];
          state_out[idx] = v;
          stT[j * 264 + m] = (f16)v;
        }
      }
    }
  }
  __syncthreads();

  // ---- phase 4: mu/sig on updated state
  for (int nt = 0; nt < 4; ++nt) {
    f32x4 acc = {0.f, 0.f, 0.f, 0.f};
#pragma unroll
    for (int ks = 0; ks < 8; ++ks) {
      f16x8 bfr = *(const f16x8*)&stT[(nt * 16 + c0) * 264 + ks * 32 + qd * 8];
      acc = __builtin_amdgcn_mfma_f32_16x16x32_f16(whfr[ks], bfr, acc, 0, 0, 0);
    }
#pragma unroll
    for (int q = 0; q < 4; ++q)
      hxl[(wave * 16 + qd * 4 + q) * 66 + nt * 16 + c0] = acc[q] + bh[wave * 16 + qd * 4 + q];
  }
  __syncthreads();
  if (tid < 64) {
    float s = 0.f;
    for (int j = 0; j < 64; ++j) s += hxl[tid * 66 + j];
    s *= (1.f / 64.f);
    hxm[tid] = s;
    mu_out[b * MOBS + tid] = s;
  }
  __syncthreads();
  {
    f16* HAf = (f16*)U;
    for (int idx = tid; idx < 4096; idx += 256) {
      int m = idx >> 6, j = idx & 63;
      HAf[m * 72 + j] = (f16)(hxl[m * 66 + j] - hxm[m]);
    }
    __syncthreads();
    f16x8 afr[2];
#pragma unroll
    for (int ks = 0; ks < 2; ++ks)
      afr[ks] = *(const f16x8*)&HAf[(wave * 16 + c0) * 72 + ks * 32 + qd * 8];
    for (int nt = 0; nt < 4; ++nt) {
      f32x4 acc = {0.f, 0.f, 0.f, 0.f};
#pragma unroll
      for (int ks = 0; ks < 2; ++ks) {
        f16x8 bfr = *(const f16x8*)&HAf[(nt * 16 + c0) * 72 + ks * 32 + qd * 8];
        acc = __builtin_amdgcn_mfma_f32_16x16x32_f16(afr[ks], bfr, acc, 0, 0, 0);
      }
#pragma unroll
      for (int q = 0; q < 4; ++q) {
        int m1 = wave * 16 + qd * 4 + q, m2 = nt * 16 + c0;
        float v = acc[q] * (1.f / 63.f) + (m1 == m2 ? r2 : 0.f);
        sig_out[b * (MOBS * MOBS) + m1 * MOBS + m2] = v;
        Pm[m1 * 65 + m2] = v + (m1 == m2 ? 1e-6f : 0.f);
      }
    }
  }
  __syncthreads();

  // ---- phase 5: loglik pieces (quad, logdet) via LDL on Pm
  if (tid < 64) {
    float v = y[b * 64 + tid] - hxm[tid];
    rv[tid] = v; r0v[tid] = v;
  }
  __syncthreads();
  for (int k = 0; k < 64; ++k) {
    float dk = Pm[k * 65 + k];
    if (n > k) {
      float f = Pm[n * 65 + k] * __builtin_amdgcn_rcpf(dk);
      for (int m = k + 1 + mg; m < 64; m += 4)
        Pm[m * 65 + n] -= Pm[m * 65 + k] * f;
    }
    __syncthreads();
  }
  if (tid < 64) dinv[tid] = __builtin_amdgcn_rcpf(Pm[tid * 65 + tid]);
  __syncthreads();
  for (int i = 0; i < 64; ++i) {
    if (tid > i && tid < 64) rv[tid] -= Pm[tid * 65 + i] * dinv[i] * rv[i];
    __syncthreads();
  }
  if (tid < 64) rv[tid] *= dinv[tid];
  __syncthreads();
  for (int i = 63; i >= 1; --i) {
    if (tid < i) rv[tid] -= Pm[i * 65 + tid] * dinv[tid] * rv[i];
    __syncthreads();
  }
  if (tid < 64) red[tid] = r0v[tid] * rv[tid];
  __syncthreads();
  if (tid == 0) {
    float q = 0.f, ld = 0.f;
    for (int m = 0; m < 64; ++m) { q += red[m]; ld += __logf(Pm[m * 65 + m]); }
    quad_g[b] = q;
    logdet_g[b] = ld;
  }
}

// ---------------- K4: final reduction (l, nis) -----------------------------
__global__ __launch_bounds__(64)
void k_reduce(const float* __restrict__ quad_g, const float* __restrict__ logdet_g,
              float* __restrict__ out_l, float* __restrict__ out_nis) {
  if (threadIdx.x == 0 && blockIdx.x == 0) {
    float l = 0.f, qs = 0.f;
    for (int b2 = 0; b2 < 32; ++b2) {
      l += -0.5f * (logdet_g[b2] + quad_g[b2]);
      qs += quad_g[b2];
    }
    out_l[0] = l;
    out_nis[0] = qs * (1.f / 32.f);
  }
}

extern "C" void kernel_launch(void* const* d_in, const int* in_sizes, int n_in,
                              void* d_out, int out_size, void* d_ws, size_t ws_size,
                              hipStream_t stream) {
  (void)in_sizes; (void)n_in; (void)out_size; (void)ws_size;
  const float* x     = (const float*)d_in[0];
  const float* y     = (const float*)d_in[1];
  const float* enkf  = (const float*)d_in[2];
  const float* W_ih  = (const float*)d_in[3];
  const float* W_hh  = (const float*)d_in[4];
  const float* bvec  = (const float*)d_in[5];
  const float* Wh    = (const float*)d_in[6];
  const float* bh    = (const float*)d_in[7];
  const float* qp    = (const float*)d_in[8];
  const float* ep    = (const float*)d_in[9];
  const float* rp    = (const float*)d_in[10];
  const float* eps_h = (const float*)d_in[11];
  const float* eps_c = (const float*)d_in[12];

  char* ws = (char*)d_ws;
  float4* xWb4   = (float4*)(ws);               // 8,388,608
  f16*   Wpack   = (f16*)(ws + 8388608);        //   524,288
  f16*   WpackIh = (f16*)(ws + 8912896);        //   524,288
  f16*   WhfP    = (f16*)(ws + 9437184);        //    32,768
  float* stateF  = (float*)(ws + 9469952);      // 2,097,152
  float* quadg   = (float*)(ws + 11567104);     //       128
  float* ldg     = (float*)(ws + 11567232);     //       128

  float* out = (float*)d_out;
  float* mu_out    = out;           // 2048
  float* sig_out   = out + 2048;    // 131072
  float* state_out = out + 133120;  // 524288
  float* l_out     = out + 657408;
  float* nis_out   = out + 657409;

  k_pack<<<257, 256, 0, stream>>>(W_hh, W_ih, Wh, Wpack, WpackIh, WhfP);
  k_xw<<<128, 512, 0, stream>>>(x, WpackIh, bvec, xWb4);
  k_lstm<<<64, 512, 0, stream>>>(xWb4, Wpack, enkf, eps_h, eps_c, qp, ep, stateF);
  k_fused<<<32, 256, 0, stream>>>(stateF, WhfP, bh, rp, y, mu_out, sig_out,
                                  state_out, quadg, ldg);
  k_reduce<<<1, 64, 0, stream>>>(quadg, ldg, l_out, nis_out);
}